// Round 1
// baseline (5680.654 us; speedup 1.0000x reference)
//
#include <hip/hip_runtime.h>
#include <hip/hip_bf16.h>

#define N_NODES 100000
#define E_EDGES 600000
#define HDIM 128
#define H2DIM 256
#define NLAYER 3
#define NSUBT 2
#define NSUB_G 20000
#define ESUB_E 200000
#define OUTD 128

typedef __bf16 bf16_t;
typedef __bf16 bf16x8 __attribute__((ext_vector_type(8)));
typedef __bf16 bf16x2 __attribute__((ext_vector_type(2)));
typedef float f32x4 __attribute__((ext_vector_type(4)));
typedef float f32x2 __attribute__((ext_vector_type(2)));

// ---------------------------------------------------------------------------
// Weight transpose: W[k][n] (row-major K x Nc, fp32) -> Wt[n][k] (bf16)
// so B-fragments (B[k][n], k contiguous per lane) are single 16B loads.
// ---------------------------------------------------------------------------
__global__ __launch_bounds__(256) void transpose_w(const float* __restrict__ W,
                                                   bf16_t* __restrict__ Wt,
                                                   int K, int Nc, long total) {
    long idx = (long)blockIdx.x * 256 + threadIdx.x;
    if (idx >= total) return;
    long kn = (long)K * Nc;
    long b = idx / kn;
    long r = idx - b * kn;
    int k = (int)(r / Nc);
    int n = (int)(r - (long)k * Nc);
    Wt[b * kn + (long)n * K + k] = (bf16_t)W[idx];
}

// ---------------------------------------------------------------------------
// Scatter-add rows: Out[sidx[e]] += X[gidx[e]]  (128 features, fp32 atomics)
// One wave per edge: 64 lanes x 2 floats.
// ---------------------------------------------------------------------------
__global__ __launch_bounds__(256) void scatter_f32(const float* __restrict__ X,
                                                   const int* __restrict__ gidx,
                                                   const int* __restrict__ sidx,
                                                   float* __restrict__ Out, int nE) {
    int e = blockIdx.x * 4 + (threadIdx.x >> 6);
    if (e >= nE) return;
    int lane = threadIdx.x & 63;
    int g = gidx[e], d = sidx[e];
    f32x2 v = *((const f32x2*)(X + (size_t)g * HDIM) + lane);
    float* op = Out + (size_t)d * HDIM + lane * 2;
    atomicAdd(op, v[0]);
    atomicAdd(op + 1, v[1]);
}

__global__ __launch_bounds__(256) void scatter_b16(const bf16_t* __restrict__ X,
                                                   const int* __restrict__ gidx,
                                                   const int* __restrict__ sidx,
                                                   float* __restrict__ Out, int nE) {
    int e = blockIdx.x * 4 + (threadIdx.x >> 6);
    if (e >= nE) return;
    int lane = threadIdx.x & 63;
    int g = gidx[e], d = sidx[e];
    bf16x2 v = *((const bf16x2*)(X + (size_t)g * HDIM) + lane);
    float* op = Out + (size_t)d * HDIM + lane * 2;
    atomicAdd(op, (float)v[0]);
    atomicAdd(op + 1, (float)v[1]);
}

// ---------------------------------------------------------------------------
// BN finalize: from column sum / sumsq -> scale/shift (training-mode batch
// stats, biased variance): y = (h-m)*rsqrt(v+eps)*g + b = h*scale + shift
// ---------------------------------------------------------------------------
__global__ void bn_finalize(const float* __restrict__ cs, const float* __restrict__ cs2,
                            const float* __restrict__ g, const float* __restrict__ b,
                            float* __restrict__ scale, float* __restrict__ shift,
                            int C, float invN) {
    int c = blockIdx.x * blockDim.x + threadIdx.x;
    if (c >= C) return;
    float m = cs[c] * invN;
    float v = cs2[c] * invN - m * m;
    float sc = g[c] * rsqrtf(v + 1e-5f);
    scale[c] = sc;
    shift[c] = b[c] - m * sc;
}

// ---------------------------------------------------------------------------
// Generic fused GEMM:  D[M x Nc] = A_eff[M x K] @ W[K x Nc] + bias
// Block: 256 thr = 4 waves (2x2). Block tile 64 rows x 128 cols.
// Wave tile: 32 rows (2 m-frags) x 64 cols (4 n-frags), mfma 16x16x32 bf16.
// grid = (ceil(M/64), Nc/128)
// amode: 0 = fp32 A;  1 = alpha*Af + Aadd (fp32, alpha=1+eps from ptr);
//        2 = bf16 A;  3 = relu(bf16A * bnScale[k] + bnShift[k])   (BN fold)
// flags: 1 = relu epilogue; 2 = accumulate into outF; 4 = column stats
// Exactly one of outF / outB is non-null.
// ---------------------------------------------------------------------------
__global__ __launch_bounds__(256) void gemm_fused(
    const float* __restrict__ Af, const float* __restrict__ Aadd,
    const float* __restrict__ alphaPtr,
    const bf16_t* __restrict__ Ab,
    const float* __restrict__ bnScale, const float* __restrict__ bnShift,
    const bf16_t* __restrict__ Wt, const float* __restrict__ bias,
    int M, int K, int Nc,
    float* __restrict__ outF, bf16_t* __restrict__ outB,
    float* __restrict__ colsum, float* __restrict__ colsumsq,
    int amode, int flags) {
    const int tid = threadIdx.x;
    const int w = tid >> 6, lane = tid & 63;
    const int q = lane >> 4, lm = lane & 15;
    const int wm = w & 1, wn = w >> 1;
    const int rowBase = blockIdx.x * 64 + wm * 32;
    const int colBase = blockIdx.y * 128 + wn * 64;

    f32x4 acc[2][4];
#pragma unroll
    for (int a = 0; a < 2; a++)
#pragma unroll
        for (int b = 0; b < 4; b++) acc[a][b] = f32x4{0.f, 0.f, 0.f, 0.f};

    float alpha = 1.0f;
    if (amode == 1) alpha += alphaPtr[0];

    for (int k0 = 0; k0 < K; k0 += 32) {
        const int kk = k0 + q * 8;
        bf16x8 bfrag[4];
#pragma unroll
        for (int ni = 0; ni < 4; ni++) {
            const int c = colBase + ni * 16 + lm;
            bfrag[ni] = *(const bf16x8*)(Wt + (size_t)c * K + kk);
        }
        float sc8[8], sh8[8];
        if (amode == 3) {
            const f32x4* sp = (const f32x4*)(bnScale + kk);
            const f32x4* hp = (const f32x4*)(bnShift + kk);
            f32x4 s0 = sp[0], s1 = sp[1], h0 = hp[0], h1 = hp[1];
#pragma unroll
            for (int j = 0; j < 4; j++) {
                sc8[j] = s0[j]; sc8[4 + j] = s1[j];
                sh8[j] = h0[j]; sh8[4 + j] = h1[j];
            }
        }
        bf16x8 afrag[2];
#pragma unroll
        for (int mi = 0; mi < 2; mi++) {
            int r = rowBase + mi * 16 + lm;
            if (r > M - 1) r = M - 1;  // clamp; stores are guarded
            const size_t off = (size_t)r * K + kk;
            if (amode == 0) {
                const f32x4* p = (const f32x4*)(Af + off);
                f32x4 a0 = p[0], a1 = p[1];
#pragma unroll
                for (int j = 0; j < 4; j++) {
                    afrag[mi][j] = (bf16_t)a0[j];
                    afrag[mi][4 + j] = (bf16_t)a1[j];
                }
            } else if (amode == 1) {
                const f32x4* p = (const f32x4*)(Af + off);
                const f32x4* p2 = (const f32x4*)(Aadd + off);
                f32x4 a0 = p[0], a1 = p[1], b0 = p2[0], b1 = p2[1];
#pragma unroll
                for (int j = 0; j < 4; j++) {
                    afrag[mi][j] = (bf16_t)(alpha * a0[j] + b0[j]);
                    afrag[mi][4 + j] = (bf16_t)(alpha * a1[j] + b1[j]);
                }
            } else if (amode == 2) {
                afrag[mi] = *(const bf16x8*)(Ab + off);
            } else {
                bf16x8 hv = *(const bf16x8*)(Ab + off);
#pragma unroll
                for (int j = 0; j < 8; j++) {
                    float f = (float)hv[j];
                    f = fmaxf(f * sc8[j] + sh8[j], 0.f);
                    afrag[mi][j] = (bf16_t)f;
                }
            }
        }
#pragma unroll
        for (int mi = 0; mi < 2; mi++)
#pragma unroll
            for (int ni = 0; ni < 4; ni++)
                acc[mi][ni] = __builtin_amdgcn_mfma_f32_16x16x32_bf16(
                    afrag[mi], bfrag[ni], acc[mi][ni], 0, 0, 0);
    }

    const bool doRelu = (flags & 1), doAccum = (flags & 2), doStats = (flags & 4);
#pragma unroll
    for (int ni = 0; ni < 4; ni++) {
        const int col = colBase + ni * 16 + lm;
        const float bv = bias[col];
        float s1 = 0.f, s2 = 0.f;
#pragma unroll
        for (int mi = 0; mi < 2; mi++) {
#pragma unroll
            for (int r = 0; r < 4; r++) {
                const int row = rowBase + mi * 16 + q * 4 + r;
                if (row < M) {
                    float v = acc[mi][ni][r] + bv;
                    if (doStats) { s1 += v; s2 += v * v; }
                    if (doRelu) v = fmaxf(v, 0.f);
                    const size_t o = (size_t)row * Nc + col;
                    if (outF) {
                        if (doAccum) outF[o] += v; else outF[o] = v;
                    } else {
                        outB[o] = (bf16_t)v;
                    }
                }
            }
        }
        if (doStats) {
            s1 += __shfl_xor(s1, 16);
            s1 += __shfl_xor(s1, 32);
            s2 += __shfl_xor(s2, 16);
            s2 += __shfl_xor(s2, 32);
            if (q == 0) {
                atomicAdd(&colsum[col], s1);
                atomicAdd(&colsumsq[col], s2);
            }
        }
    }
}

// ---------------------------------------------------------------------------
extern "C" void kernel_launch(void* const* d_in, const int* in_sizes, int n_in,
                              void* d_out, int out_size, void* d_ws, size_t ws_size,
                              hipStream_t stream) {
    const float* x_in   = (const float*)d_in[0];
    const int*   ei     = (const int*)d_in[1];
    const int*   se0    = (const int*)d_in[2];
    const int*   se1    = (const int*)d_in[3];
    const float* msg_w1 = (const float*)d_in[4];
    const float* msg_b1 = (const float*)d_in[5];
    const float* bn_g   = (const float*)d_in[6];
    const float* bn_b   = (const float*)d_in[7];
    const float* msg_w2 = (const float*)d_in[8];
    const float* msg_b2 = (const float*)d_in[9];
    const float* eps_g  = (const float*)d_in[10];
    const float* n2s_w1 = (const float*)d_in[11];
    const float* n2s_b1 = (const float*)d_in[12];
    const float* n2s_w2 = (const float*)d_in[13];
    const float* n2s_b2 = (const float*)d_in[14];
    const float* s2n_w1 = (const float*)d_in[15];
    const float* s2n_b1 = (const float*)d_in[16];
    const float* s2n_w2 = (const float*)d_in[17];
    const float* s2n_b2 = (const float*)d_in[18];
    const float* out_w1 = (const float*)d_in[19];
    const float* out_b1 = (const float*)d_in[20];
    const float* out_w2 = (const float*)d_in[21];
    const float* out_b2 = (const float*)d_in[22];
    float* out = (float*)d_out;

    char* ws = (char*)d_ws;
    size_t off = 0;
    auto alloc = [&](size_t bytes) -> char* {
        char* p = ws + off;
        off += (bytes + 255) & ~(size_t)255;
        return p;
    };
    float*  xbuf   = (float*)alloc((size_t)N_NODES * HDIM * 4);
    float*  aggbuf = (float*)alloc((size_t)N_NODES * HDIM * 4);   // also msg buffer
    bf16_t* hbuf   = (bf16_t*)alloc((size_t)N_NODES * H2DIM * 2);
    float*  sxsum  = (float*)alloc((size_t)NSUB_G * HDIM * 4);
    bf16_t* shbuf  = (bf16_t*)alloc((size_t)NSUB_G * H2DIM * 2);
    bf16_t* sxout  = (bf16_t*)alloc((size_t)NSUB_G * HDIM * 2);
    const size_t WSZ = (size_t)HDIM * H2DIM;  // 32768 elems per matrix
    bf16_t* wt_msg1 = (bf16_t*)alloc(NLAYER * WSZ * 2);
    bf16_t* wt_msg2 = (bf16_t*)alloc(NLAYER * WSZ * 2);
    bf16_t* wt_n2s1 = (bf16_t*)alloc(NLAYER * NSUBT * WSZ * 2);
    bf16_t* wt_n2s2 = (bf16_t*)alloc(NLAYER * NSUBT * WSZ * 2);
    bf16_t* wt_s2n1 = (bf16_t*)alloc(NLAYER * NSUBT * WSZ * 2);
    bf16_t* wt_s2n2 = (bf16_t*)alloc(NLAYER * NSUBT * WSZ * 2);
    bf16_t* wt_out1 = (bf16_t*)alloc(WSZ * 2);
    bf16_t* wt_out2 = (bf16_t*)alloc(WSZ * 2);
    float* colsum   = (float*)alloc(H2DIM * 4);
    float* colsumsq = (float*)alloc(H2DIM * 4);
    float* bnscale  = (float*)alloc(H2DIM * 4);
    float* bnshift  = (float*)alloc(H2DIM * 4);
    (void)ws_size; (void)in_sizes; (void)n_in; (void)out_size;

    // --- weight transposes (fp32 -> bf16 n-major) ---
    auto tr = [&](const float* W, bf16_t* Wt, int K, int Nc, int batch) {
        long total = (long)batch * K * Nc;
        int blocks = (int)((total + 255) / 256);
        transpose_w<<<blocks, 256, 0, stream>>>(W, Wt, K, Nc, total);
    };
    tr(msg_w1, wt_msg1, HDIM, H2DIM, NLAYER);
    tr(msg_w2, wt_msg2, H2DIM, HDIM, NLAYER);
    tr(n2s_w1, wt_n2s1, HDIM, H2DIM, NLAYER * NSUBT);
    tr(n2s_w2, wt_n2s2, H2DIM, HDIM, NLAYER * NSUBT);
    tr(s2n_w1, wt_s2n1, HDIM, H2DIM, NLAYER * NSUBT);
    tr(s2n_w2, wt_s2n2, H2DIM, HDIM, NLAYER * NSUBT);
    tr(out_w1, wt_out1, HDIM, H2DIM, 1);
    tr(out_w2, wt_out2, H2DIM, OUTD, 1);

    hipMemcpyAsync(xbuf, x_in, (size_t)N_NODES * HDIM * 4,
                   hipMemcpyDeviceToDevice, stream);

    auto gemm = [&](const float* Af, const float* Aadd, const float* alphaPtr,
                    const bf16_t* Ab, const float* bnS, const float* bnH,
                    const bf16_t* Wt, const float* bias, int M, int K, int Nc,
                    float* oF, bf16_t* oB, float* cs, float* cs2,
                    int amode, int flags) {
        dim3 g((M + 63) / 64, Nc / 128);
        gemm_fused<<<g, 256, 0, stream>>>(Af, Aadd, alphaPtr, Ab, bnS, bnH, Wt,
                                          bias, M, K, Nc, oF, oB, cs, cs2,
                                          amode, flags);
    };

    const int* src = ei;
    const int* dst = ei + E_EDGES;

    for (int i = 0; i < NLAYER; i++) {
        // --- GINConv aggregation: agg = segment_sum(x[src], dst) ---
        hipMemsetAsync(aggbuf, 0, (size_t)N_NODES * HDIM * 4, stream);
        scatter_f32<<<(E_EDGES + 3) / 4, 256, 0, stream>>>(xbuf, src, dst, aggbuf, E_EDGES);
        // --- h = ((1+eps)x + agg) @ W1 + b1 ; column stats for BN ---
        hipMemsetAsync(colsum, 0, H2DIM * 4, stream);
        hipMemsetAsync(colsumsq, 0, H2DIM * 4, stream);
        gemm(xbuf, aggbuf, eps_g + i, nullptr, nullptr, nullptr,
             wt_msg1 + (size_t)i * WSZ, msg_b1 + (size_t)i * H2DIM,
             N_NODES, HDIM, H2DIM, nullptr, hbuf, colsum, colsumsq, 1, 4);
        bn_finalize<<<1, 256, 0, stream>>>(colsum, colsumsq, bn_g + (size_t)i * H2DIM,
                                           bn_b + (size_t)i * H2DIM, bnscale, bnshift,
                                           H2DIM, 1.0f / N_NODES);
        // --- x = relu(BN(h)) @ W2 + b2 ---
        gemm(nullptr, nullptr, nullptr, hbuf, bnscale, bnshift,
             wt_msg2 + (size_t)i * WSZ, msg_b2 + (size_t)i * HDIM,
             N_NODES, H2DIM, HDIM, xbuf, nullptr, nullptr, nullptr, 3, 0);

        // --- substructure message passing ---
        for (int s = 0; s < NSUBT; s++) {
            const int* row = (s == 0 ? se0 : se1);
            const int* col = row + ESUB_E;
            const size_t widx = ((size_t)i * NSUBT + s) * WSZ;
            const size_t b1o = ((size_t)i * NSUBT + s) * H2DIM;
            const size_t b2o = ((size_t)i * NSUBT + s) * HDIM;
            hipMemsetAsync(sxsum, 0, (size_t)NSUB_G * HDIM * 4, stream);
            scatter_f32<<<(ESUB_E + 3) / 4, 256, 0, stream>>>(xbuf, row, col, sxsum, ESUB_E);
            // sx mlp: relu(sx@w1+b1)@w2+b2
            gemm(sxsum, nullptr, nullptr, nullptr, nullptr, nullptr,
                 wt_n2s1 + widx, n2s_b1 + b1o, NSUB_G, HDIM, H2DIM,
                 nullptr, shbuf, nullptr, nullptr, 0, 1);
            gemm(nullptr, nullptr, nullptr, shbuf, nullptr, nullptr,
                 wt_n2s2 + widx, n2s_b2 + b2o, NSUB_G, H2DIM, HDIM,
                 nullptr, sxout, nullptr, nullptr, 2, 0);
            // msg = segment_sum(sx[col], row)
            hipMemsetAsync(aggbuf, 0, (size_t)N_NODES * HDIM * 4, stream);
            scatter_b16<<<(ESUB_E + 3) / 4, 256, 0, stream>>>(sxout, col, row, aggbuf, ESUB_E);
            // x += relu(msg@w1+b1)@w2+b2
            gemm(aggbuf, nullptr, nullptr, nullptr, nullptr, nullptr,
                 wt_s2n1 + widx, s2n_b1 + b1o, N_NODES, HDIM, H2DIM,
                 nullptr, hbuf, nullptr, nullptr, 0, 1);
            gemm(nullptr, nullptr, nullptr, hbuf, nullptr, nullptr,
                 wt_s2n2 + widx, s2n_b2 + b2o, N_NODES, H2DIM, HDIM,
                 xbuf, nullptr, nullptr, nullptr, 2, 2);
        }
    }
    // --- output head: relu(x@w1+b1)@w2+b2 ---
    gemm(xbuf, nullptr, nullptr, nullptr, nullptr, nullptr,
         wt_out1, out_b1, N_NODES, HDIM, H2DIM, nullptr, hbuf, nullptr, nullptr, 0, 1);
    gemm(nullptr, nullptr, nullptr, hbuf, nullptr, nullptr,
         wt_out2, out_b2, N_NODES, H2DIM, OUTD, out, nullptr, nullptr, nullptr, 2, 0);
}

// Round 2
// 2691.610 us; speedup vs baseline: 2.1105x; 2.1105x over previous
//
#include <hip/hip_runtime.h>
#include <hip/hip_bf16.h>

#define N_NODES 100000
#define E_EDGES 600000
#define HDIM 128
#define H2DIM 256
#define NLAYER 3
#define NSUBT 2
#define NSUB_G 20000
#define ESUB_E 200000
#define OUTD 128

typedef __bf16 bf16_t;
typedef __bf16 bf16x8 __attribute__((ext_vector_type(8)));
typedef __bf16 bf16x2 __attribute__((ext_vector_type(2)));
typedef float f32x4 __attribute__((ext_vector_type(4)));
typedef float f32x2 __attribute__((ext_vector_type(2)));

// ---------------------------------------------------------------------------
// Weight transpose: W[k][n] (row-major K x Nc, fp32) -> Wt[n][k] (bf16)
// ---------------------------------------------------------------------------
__global__ __launch_bounds__(256) void transpose_w(const float* __restrict__ W,
                                                   bf16_t* __restrict__ Wt,
                                                   int K, int Nc, long total) {
    long idx = (long)blockIdx.x * 256 + threadIdx.x;
    if (idx >= total) return;
    long kn = (long)K * Nc;
    long b = idx / kn;
    long r = idx - b * kn;
    int k = (int)(r / Nc);
    int n = (int)(r - (long)k * Nc);
    Wt[b * kn + (long)n * K + k] = (bf16_t)W[idx];
}

// ---------------------------------------------------------------------------
// CSR build: histogram -> hierarchical exclusive scan -> placement
// ---------------------------------------------------------------------------
__global__ __launch_bounds__(256) void hist_k(const int* __restrict__ idx,
                                              int* __restrict__ counts, int nE) {
    int e = blockIdx.x * 256 + threadIdx.x;
    if (e < nE) atomicAdd(&counts[idx[e]], 1);
}

// each block scans 1024 elements (4/thread); writes block-local exclusive scan
// + per-block totals
__global__ __launch_bounds__(256) void scan1_k(const int* __restrict__ in,
                                               int* __restrict__ out,
                                               int* __restrict__ bsum, int n) {
    __shared__ int tmp[256];
    const int t = threadIdx.x;
    const long base = (long)blockIdx.x * 1024 + (long)t * 4;
    int v[4];
    int s = 0;
#pragma unroll
    for (int j = 0; j < 4; j++) {
        long i = base + j;
        int x = (i < n) ? in[i] : 0;
        v[j] = s;
        s += x;
    }
    tmp[t] = s;
    __syncthreads();
    int inc = s;
    for (int off = 1; off < 256; off <<= 1) {
        int y = (t >= off) ? tmp[t - off] : 0;
        __syncthreads();
        inc += y;
        tmp[t] = inc;
        __syncthreads();
    }
    const int toff = inc - s;  // exclusive offset of this thread within block
#pragma unroll
    for (int j = 0; j < 4; j++) {
        long i = base + j;
        if (i < n) out[i] = v[j] + toff;
    }
    if (t == 255) bsum[blockIdx.x] = inc;
}

// single block: exclusive-scan the (<=256) block totals in place
__global__ __launch_bounds__(256) void scan2_k(int* __restrict__ bsum, int nb) {
    __shared__ int tmp[256];
    const int t = threadIdx.x;
    int x = (t < nb) ? bsum[t] : 0;
    tmp[t] = x;
    __syncthreads();
    int inc = x;
    for (int off = 1; off < 256; off <<= 1) {
        int y = (t >= off) ? tmp[t - off] : 0;
        __syncthreads();
        inc += y;
        tmp[t] = inc;
        __syncthreads();
    }
    if (t < nb) bsum[t] = inc - x;
}

// add block offsets; write rowptr and work (running cursor) copies
__global__ __launch_bounds__(256) void scan3_k(const int* __restrict__ partial,
                                               const int* __restrict__ bsum,
                                               int* __restrict__ rowptr,
                                               int* __restrict__ work,
                                               int n, int total) {
    long i = (long)blockIdx.x * 256 + threadIdx.x;
    if (i < n) {
        int v = partial[i] + bsum[i >> 10];
        rowptr[i] = v;
        work[i] = v;
    }
    if (i == 0) rowptr[n] = total;
}

// place gather-indices into CSR order
__global__ __launch_bounds__(256) void csr_place(const int* __restrict__ idx,
                                                 const int* __restrict__ gsrc,
                                                 int* __restrict__ work,
                                                 int* __restrict__ gat, int nE) {
    int e = blockIdx.x * 256 + threadIdx.x;
    if (e < nE) {
        int p = atomicAdd(&work[idx[e]], 1);
        gat[p] = gsrc[e];
    }
}

// ---------------------------------------------------------------------------
// Gather-based segment sums (one wave per segment, 2 floats/lane). No atomics.
// ---------------------------------------------------------------------------
__global__ __launch_bounds__(256) void segsum_gin(const float* __restrict__ X,
                                                  const float* __restrict__ epsPtr,
                                                  const int* __restrict__ rowptr,
                                                  const int* __restrict__ gat,
                                                  bf16_t* __restrict__ out, int nseg) {
    int seg = blockIdx.x * 4 + (threadIdx.x >> 6);
    if (seg >= nseg) return;
    int lane = threadIdx.x & 63;
    float alpha = 1.f + epsPtr[0];
    f32x2 xv = *((const f32x2*)(X + (size_t)seg * HDIM) + lane);
    float a0 = alpha * xv[0], a1 = alpha * xv[1];
    int s0 = rowptr[seg], s1 = rowptr[seg + 1];
    for (int e = s0; e < s1; e++) {
        int g = gat[e];
        f32x2 v = *((const f32x2*)(X + (size_t)g * HDIM) + lane);
        a0 += v[0];
        a1 += v[1];
    }
    bf16x2 o;
    o[0] = (bf16_t)a0;
    o[1] = (bf16_t)a1;
    *((bf16x2*)(out + (size_t)seg * HDIM) + lane) = o;
}

__global__ __launch_bounds__(256) void segsum_f32(const float* __restrict__ X,
                                                  const int* __restrict__ rowptr,
                                                  const int* __restrict__ gat,
                                                  bf16_t* __restrict__ out, int nseg) {
    int seg = blockIdx.x * 4 + (threadIdx.x >> 6);
    if (seg >= nseg) return;
    int lane = threadIdx.x & 63;
    float a0 = 0.f, a1 = 0.f;
    int s0 = rowptr[seg], s1 = rowptr[seg + 1];
    for (int e = s0; e < s1; e++) {
        int g = gat[e];
        f32x2 v = *((const f32x2*)(X + (size_t)g * HDIM) + lane);
        a0 += v[0];
        a1 += v[1];
    }
    bf16x2 o;
    o[0] = (bf16_t)a0;
    o[1] = (bf16_t)a1;
    *((bf16x2*)(out + (size_t)seg * HDIM) + lane) = o;
}

__global__ __launch_bounds__(256) void segsum_b16(const bf16_t* __restrict__ X,
                                                  const int* __restrict__ rowptr,
                                                  const int* __restrict__ gat,
                                                  bf16_t* __restrict__ out, int nseg) {
    int seg = blockIdx.x * 4 + (threadIdx.x >> 6);
    if (seg >= nseg) return;
    int lane = threadIdx.x & 63;
    float a0 = 0.f, a1 = 0.f;
    int s0 = rowptr[seg], s1 = rowptr[seg + 1];
    for (int e = s0; e < s1; e++) {
        int g = gat[e];
        bf16x2 v = *((const bf16x2*)(X + (size_t)g * HDIM) + lane);
        a0 += (float)v[0];
        a1 += (float)v[1];
    }
    bf16x2 o;
    o[0] = (bf16_t)a0;
    o[1] = (bf16_t)a1;
    *((bf16x2*)(out + (size_t)seg * HDIM) + lane) = o;
}

// ---------------------------------------------------------------------------
// BN finalize
// ---------------------------------------------------------------------------
__global__ void bn_finalize(const float* __restrict__ cs, const float* __restrict__ cs2,
                            const float* __restrict__ g, const float* __restrict__ b,
                            float* __restrict__ scale, float* __restrict__ shift,
                            int C, float invN) {
    int c = blockIdx.x * blockDim.x + threadIdx.x;
    if (c >= C) return;
    float m = cs[c] * invN;
    float v = cs2[c] * invN - m * m;
    float sc = g[c] * rsqrtf(v + 1e-5f);
    scale[c] = sc;
    shift[c] = b[c] - m * sc;
}

// ---------------------------------------------------------------------------
// Fused GEMM:  D[M x Nc] = A_eff[M x K] @ W[K x Nc] + bias
// amode: 0 = fp32 A; 2 = bf16 A; 3 = relu(bf16A * bnScale[k] + bnShift[k])
// flags: 1 = relu epilogue; 2 = accumulate into outF; 4 = column stats
// ---------------------------------------------------------------------------
__global__ __launch_bounds__(256) void gemm_fused(
    const float* __restrict__ Af,
    const bf16_t* __restrict__ Ab,
    const float* __restrict__ bnScale, const float* __restrict__ bnShift,
    const bf16_t* __restrict__ Wt, const float* __restrict__ bias,
    int M, int K, int Nc,
    float* __restrict__ outF, bf16_t* __restrict__ outB,
    float* __restrict__ colsum, float* __restrict__ colsumsq,
    int amode, int flags) {
    const int tid = threadIdx.x;
    const int w = tid >> 6, lane = tid & 63;
    const int q = lane >> 4, lm = lane & 15;
    const int wm = w & 1, wn = w >> 1;
    const int rowBase = blockIdx.x * 64 + wm * 32;
    const int colBase = blockIdx.y * 128 + wn * 64;

    f32x4 acc[2][4];
#pragma unroll
    for (int a = 0; a < 2; a++)
#pragma unroll
        for (int b = 0; b < 4; b++) acc[a][b] = f32x4{0.f, 0.f, 0.f, 0.f};

    for (int k0 = 0; k0 < K; k0 += 32) {
        const int kk = k0 + q * 8;
        bf16x8 bfrag[4];
#pragma unroll
        for (int ni = 0; ni < 4; ni++) {
            const int c = colBase + ni * 16 + lm;
            bfrag[ni] = *(const bf16x8*)(Wt + (size_t)c * K + kk);
        }
        float sc8[8], sh8[8];
        if (amode == 3) {
            const f32x4* sp = (const f32x4*)(bnScale + kk);
            const f32x4* hp = (const f32x4*)(bnShift + kk);
            f32x4 s0 = sp[0], s1 = sp[1], h0 = hp[0], h1 = hp[1];
#pragma unroll
            for (int j = 0; j < 4; j++) {
                sc8[j] = s0[j]; sc8[4 + j] = s1[j];
                sh8[j] = h0[j]; sh8[4 + j] = h1[j];
            }
        }
        bf16x8 afrag[2];
#pragma unroll
        for (int mi = 0; mi < 2; mi++) {
            int r = rowBase + mi * 16 + lm;
            if (r > M - 1) r = M - 1;  // clamp; stores are guarded
            const size_t off = (size_t)r * K + kk;
            if (amode == 0) {
                const f32x4* p = (const f32x4*)(Af + off);
                f32x4 a0 = p[0], a1 = p[1];
#pragma unroll
                for (int j = 0; j < 4; j++) {
                    afrag[mi][j] = (bf16_t)a0[j];
                    afrag[mi][4 + j] = (bf16_t)a1[j];
                }
            } else if (amode == 2) {
                afrag[mi] = *(const bf16x8*)(Ab + off);
            } else {
                bf16x8 hv = *(const bf16x8*)(Ab + off);
#pragma unroll
                for (int j = 0; j < 8; j++) {
                    float f = (float)hv[j];
                    f = fmaxf(f * sc8[j] + sh8[j], 0.f);
                    afrag[mi][j] = (bf16_t)f;
                }
            }
        }
#pragma unroll
        for (int mi = 0; mi < 2; mi++)
#pragma unroll
            for (int ni = 0; ni < 4; ni++)
                acc[mi][ni] = __builtin_amdgcn_mfma_f32_16x16x32_bf16(
                    afrag[mi], bfrag[ni], acc[mi][ni], 0, 0, 0);
    }

    const bool doRelu = (flags & 1), doAccum = (flags & 2), doStats = (flags & 4);
#pragma unroll
    for (int ni = 0; ni < 4; ni++) {
        const int col = colBase + ni * 16 + lm;
        const float bv = bias[col];
        float s1 = 0.f, s2 = 0.f;
#pragma unroll
        for (int mi = 0; mi < 2; mi++) {
#pragma unroll
            for (int r = 0; r < 4; r++) {
                const int row = rowBase + mi * 16 + q * 4 + r;
                if (row < M) {
                    float v = acc[mi][ni][r] + bv;
                    if (doStats) { s1 += v; s2 += v * v; }
                    if (doRelu) v = fmaxf(v, 0.f);
                    const size_t o = (size_t)row * Nc + col;
                    if (outF) {
                        if (doAccum) outF[o] += v; else outF[o] = v;
                    } else {
                        outB[o] = (bf16_t)v;
                    }
                }
            }
        }
        if (doStats) {
            s1 += __shfl_xor(s1, 16);
            s1 += __shfl_xor(s1, 32);
            s2 += __shfl_xor(s2, 16);
            s2 += __shfl_xor(s2, 32);
            if (q == 0) {
                atomicAdd(&colsum[col], s1);
                atomicAdd(&colsumsq[col], s2);
            }
        }
    }
}

// ---------------------------------------------------------------------------
extern "C" void kernel_launch(void* const* d_in, const int* in_sizes, int n_in,
                              void* d_out, int out_size, void* d_ws, size_t ws_size,
                              hipStream_t stream) {
    const float* x_in   = (const float*)d_in[0];
    const int*   ei     = (const int*)d_in[1];
    const int*   se0    = (const int*)d_in[2];
    const int*   se1    = (const int*)d_in[3];
    const float* msg_w1 = (const float*)d_in[4];
    const float* msg_b1 = (const float*)d_in[5];
    const float* bn_g   = (const float*)d_in[6];
    const float* bn_b   = (const float*)d_in[7];
    const float* msg_w2 = (const float*)d_in[8];
    const float* msg_b2 = (const float*)d_in[9];
    const float* eps_g  = (const float*)d_in[10];
    const float* n2s_w1 = (const float*)d_in[11];
    const float* n2s_b1 = (const float*)d_in[12];
    const float* n2s_w2 = (const float*)d_in[13];
    const float* n2s_b2 = (const float*)d_in[14];
    const float* s2n_w1 = (const float*)d_in[15];
    const float* s2n_b1 = (const float*)d_in[16];
    const float* s2n_w2 = (const float*)d_in[17];
    const float* s2n_b2 = (const float*)d_in[18];
    const float* out_w1 = (const float*)d_in[19];
    const float* out_b1 = (const float*)d_in[20];
    const float* out_w2 = (const float*)d_in[21];
    const float* out_b2 = (const float*)d_in[22];
    float* out = (float*)d_out;

    char* ws = (char*)d_ws;
    size_t off = 0;
    auto alloc = [&](size_t bytes) -> char* {
        char* p = ws + off;
        off += (bytes + 255) & ~(size_t)255;
        return p;
    };
    float*  xbuf   = (float*)alloc((size_t)N_NODES * HDIM * 4);
    bf16_t* xcomb  = (bf16_t*)alloc((size_t)N_NODES * HDIM * 2);  // GIN-comb / s2n msg
    bf16_t* hbuf   = (bf16_t*)alloc((size_t)N_NODES * H2DIM * 2);
    bf16_t* sxsum  = (bf16_t*)alloc((size_t)NSUB_G * HDIM * 2);
    bf16_t* shbuf  = (bf16_t*)alloc((size_t)NSUB_G * H2DIM * 2);
    bf16_t* sxout  = (bf16_t*)alloc((size_t)NSUB_G * HDIM * 2);
    const size_t WSZ = (size_t)HDIM * H2DIM;
    bf16_t* wt_msg1 = (bf16_t*)alloc(NLAYER * WSZ * 2);
    bf16_t* wt_msg2 = (bf16_t*)alloc(NLAYER * WSZ * 2);
    bf16_t* wt_n2s1 = (bf16_t*)alloc(NLAYER * NSUBT * WSZ * 2);
    bf16_t* wt_n2s2 = (bf16_t*)alloc(NLAYER * NSUBT * WSZ * 2);
    bf16_t* wt_s2n1 = (bf16_t*)alloc(NLAYER * NSUBT * WSZ * 2);
    bf16_t* wt_s2n2 = (bf16_t*)alloc(NLAYER * NSUBT * WSZ * 2);
    bf16_t* wt_out1 = (bf16_t*)alloc(WSZ * 2);
    bf16_t* wt_out2 = (bf16_t*)alloc(WSZ * 2);
    float* colsum   = (float*)alloc(H2DIM * 4);
    float* colsumsq = (float*)alloc(H2DIM * 4);
    float* bnscale  = (float*)alloc(H2DIM * 4);
    float* bnshift  = (float*)alloc(H2DIM * 4);
    // CSR persistent
    int* rp_gin   = (int*)alloc((N_NODES + 1) * 4);
    int* gat_gin  = (int*)alloc((size_t)E_EDGES * 4);
    int* rp_n2s0  = (int*)alloc((NSUB_G + 1) * 4);
    int* gat_n2s0 = (int*)alloc((size_t)ESUB_E * 4);
    int* rp_n2s1  = (int*)alloc((NSUB_G + 1) * 4);
    int* gat_n2s1 = (int*)alloc((size_t)ESUB_E * 4);
    int* rp_s2n0  = (int*)alloc((N_NODES + 1) * 4);
    int* gat_s2n0 = (int*)alloc((size_t)ESUB_E * 4);
    int* rp_s2n1  = (int*)alloc((N_NODES + 1) * 4);
    int* gat_s2n1 = (int*)alloc((size_t)ESUB_E * 4);
    // CSR temporaries (reused across builds; sequential on stream)
    int* counts  = (int*)alloc((N_NODES + 1) * 4);
    int* partial = (int*)alloc((size_t)N_NODES * 4);
    int* bsum    = (int*)alloc(512 * 4);
    (void)ws_size; (void)in_sizes; (void)n_in; (void)out_size;

    // --- weight transposes ---
    auto tr = [&](const float* W, bf16_t* Wt, int K, int Nc, int batch) {
        long total = (long)batch * K * Nc;
        int blocks = (int)((total + 255) / 256);
        transpose_w<<<blocks, 256, 0, stream>>>(W, Wt, K, Nc, total);
    };
    tr(msg_w1, wt_msg1, HDIM, H2DIM, NLAYER);
    tr(msg_w2, wt_msg2, H2DIM, HDIM, NLAYER);
    tr(n2s_w1, wt_n2s1, HDIM, H2DIM, NLAYER * NSUBT);
    tr(n2s_w2, wt_n2s2, H2DIM, HDIM, NLAYER * NSUBT);
    tr(s2n_w1, wt_s2n1, HDIM, H2DIM, NLAYER * NSUBT);
    tr(s2n_w2, wt_s2n2, H2DIM, HDIM, NLAYER * NSUBT);
    tr(out_w1, wt_out1, HDIM, H2DIM, 1);
    tr(out_w2, wt_out2, H2DIM, OUTD, 1);

    // --- CSR builds (idx = segment index per edge, gsrc = gather index) ---
    auto build_csr = [&](const int* idx, const int* gsrc, int nE, int nseg,
                         int* rowptr, int* gat) {
        hipMemsetAsync(counts, 0, (size_t)nseg * 4, stream);
        hist_k<<<(nE + 255) / 256, 256, 0, stream>>>(idx, counts, nE);
        int nb = (nseg + 1023) / 1024;
        scan1_k<<<nb, 256, 0, stream>>>(counts, partial, bsum, nseg);
        scan2_k<<<1, 256, 0, stream>>>(bsum, nb);
        scan3_k<<<(nseg + 255) / 256, 256, 0, stream>>>(partial, bsum, rowptr,
                                                        counts, nseg, nE);
        csr_place<<<(nE + 255) / 256, 256, 0, stream>>>(idx, gsrc, counts, gat, nE);
    };
    const int* src = ei;
    const int* dst = ei + E_EDGES;
    build_csr(dst, src, E_EDGES, N_NODES, rp_gin, gat_gin);               // GIN by dst
    build_csr(se0 + ESUB_E, se0, ESUB_E, NSUB_G, rp_n2s0, gat_n2s0);      // n2s0 by col
    build_csr(se1 + ESUB_E, se1, ESUB_E, NSUB_G, rp_n2s1, gat_n2s1);      // n2s1 by col
    build_csr(se0, se0 + ESUB_E, ESUB_E, N_NODES, rp_s2n0, gat_s2n0);     // s2n0 by row
    build_csr(se1, se1 + ESUB_E, ESUB_E, N_NODES, rp_s2n1, gat_s2n1);     // s2n1 by row

    hipMemcpyAsync(xbuf, x_in, (size_t)N_NODES * HDIM * 4,
                   hipMemcpyDeviceToDevice, stream);

    auto gemm = [&](const float* Af, const bf16_t* Ab, const float* bnS,
                    const float* bnH, const bf16_t* Wt, const float* bias,
                    int M, int K, int Nc, float* oF, bf16_t* oB,
                    float* cs, float* cs2, int amode, int flags) {
        dim3 g((M + 63) / 64, Nc / 128);
        gemm_fused<<<g, 256, 0, stream>>>(Af, Ab, bnS, bnH, Wt, bias, M, K, Nc,
                                          oF, oB, cs, cs2, amode, flags);
    };

    for (int i = 0; i < NLAYER; i++) {
        // --- GIN aggregation fused with (1+eps)x combine -> bf16 ---
        segsum_gin<<<(N_NODES + 3) / 4, 256, 0, stream>>>(
            xbuf, eps_g + i, rp_gin, gat_gin, xcomb, N_NODES);
        // --- h = xcomb @ W1 + b1 ; column stats for BN ---
        hipMemsetAsync(colsum, 0, H2DIM * 4, stream);
        hipMemsetAsync(colsumsq, 0, H2DIM * 4, stream);
        gemm(nullptr, xcomb, nullptr, nullptr,
             wt_msg1 + (size_t)i * WSZ, msg_b1 + (size_t)i * H2DIM,
             N_NODES, HDIM, H2DIM, nullptr, hbuf, colsum, colsumsq, 2, 4);
        bn_finalize<<<1, 256, 0, stream>>>(colsum, colsumsq, bn_g + (size_t)i * H2DIM,
                                           bn_b + (size_t)i * H2DIM, bnscale, bnshift,
                                           H2DIM, 1.0f / N_NODES);
        // --- x = relu(BN(h)) @ W2 + b2 ---
        gemm(nullptr, hbuf, bnscale, bnshift,
             wt_msg2 + (size_t)i * WSZ, msg_b2 + (size_t)i * HDIM,
             N_NODES, H2DIM, HDIM, xbuf, nullptr, nullptr, nullptr, 3, 0);

        // --- substructure message passing ---
        for (int s = 0; s < NSUBT; s++) {
            const int* rp_n2s = (s == 0 ? rp_n2s0 : rp_n2s1);
            const int* gt_n2s = (s == 0 ? gat_n2s0 : gat_n2s1);
            const int* rp_s2n = (s == 0 ? rp_s2n0 : rp_s2n1);
            const int* gt_s2n = (s == 0 ? gat_s2n0 : gat_s2n1);
            const size_t widx = ((size_t)i * NSUBT + s) * WSZ;
            const size_t b1o = ((size_t)i * NSUBT + s) * H2DIM;
            const size_t b2o = ((size_t)i * NSUBT + s) * HDIM;
            // sx = segment_sum(x[row], col)  -> bf16
            segsum_f32<<<(NSUB_G + 3) / 4, 256, 0, stream>>>(
                xbuf, rp_n2s, gt_n2s, sxsum, NSUB_G);
            // sx = relu(sx@w1+b1)@w2+b2
            gemm(nullptr, sxsum, nullptr, nullptr,
                 wt_n2s1 + widx, n2s_b1 + b1o, NSUB_G, HDIM, H2DIM,
                 nullptr, shbuf, nullptr, nullptr, 2, 1);
            gemm(nullptr, shbuf, nullptr, nullptr,
                 wt_n2s2 + widx, n2s_b2 + b2o, NSUB_G, H2DIM, HDIM,
                 nullptr, sxout, nullptr, nullptr, 2, 0);
            // msg = segment_sum(sx[col], row) -> bf16
            segsum_b16<<<(N_NODES + 3) / 4, 256, 0, stream>>>(
                sxout, rp_s2n, gt_s2n, xcomb, N_NODES);
            // x += relu(msg@w1+b1)@w2+b2
            gemm(nullptr, xcomb, nullptr, nullptr,
                 wt_s2n1 + widx, s2n_b1 + b1o, N_NODES, HDIM, H2DIM,
                 nullptr, hbuf, nullptr, nullptr, 2, 1);
            gemm(nullptr, hbuf, nullptr, nullptr,
                 wt_s2n2 + widx, s2n_b2 + b2o, N_NODES, H2DIM, HDIM,
                 xbuf, nullptr, nullptr, nullptr, 2, 2);
        }
    }
    // --- output head ---
    gemm(xbuf, nullptr, nullptr, nullptr,
         wt_out1, out_b1, N_NODES, HDIM, H2DIM, nullptr, hbuf, nullptr, nullptr, 0, 1);
    gemm(nullptr, hbuf, nullptr, nullptr,
         wt_out2, out_b2, N_NODES, H2DIM, OUTD, out, nullptr, nullptr, nullptr, 2, 0);
}

// Round 3
// 2348.199 us; speedup vs baseline: 2.4192x; 1.1462x over previous
//
#include <hip/hip_runtime.h>
#include <hip/hip_bf16.h>

#define N_NODES 100000
#define E_EDGES 600000
#define HDIM 128
#define H2DIM 256
#define NLAYER 3
#define NSUBT 2
#define NSUB_G 20000
#define ESUB_E 200000
#define OUTD 128

typedef __bf16 bf16_t;
typedef __bf16 bf16x8 __attribute__((ext_vector_type(8)));
typedef __bf16 bf16x4 __attribute__((ext_vector_type(4)));
typedef __bf16 bf16x2 __attribute__((ext_vector_type(2)));
typedef float f32x4 __attribute__((ext_vector_type(4)));
typedef float f32x2 __attribute__((ext_vector_type(2)));

// async global->LDS, 16B per lane; LDS dest = base + lane*16 (wave-uniform base)
#define GLOAD_LDS16(gp, lp)                                                      \
    __builtin_amdgcn_global_load_lds(                                            \
        (const __attribute__((address_space(1))) void*)(gp),                     \
        (__attribute__((address_space(3))) void*)(lp), 16, 0, 0)

// ---------------------------------------------------------------------------
// Weight transpose: W[k][n] (row-major K x Nc, fp32) -> Wt[n][k] (bf16)
// ---------------------------------------------------------------------------
__global__ __launch_bounds__(256) void transpose_w(const float* __restrict__ W,
                                                   bf16_t* __restrict__ Wt,
                                                   int K, int Nc, long total) {
    long idx = (long)blockIdx.x * 256 + threadIdx.x;
    if (idx >= total) return;
    long kn = (long)K * Nc;
    long b = idx / kn;
    long r = idx - b * kn;
    int k = (int)(r / Nc);
    int n = (int)(r - (long)k * Nc);
    Wt[b * kn + (long)n * K + k] = (bf16_t)W[idx];
}

__global__ __launch_bounds__(256) void cast_f2b(const float* __restrict__ in,
                                                bf16_t* __restrict__ out, long n) {
    long i = ((long)blockIdx.x * 256 + threadIdx.x) * 4;
    if (i >= n) return;
    f32x4 v = *(const f32x4*)(in + i);
    bf16x4 o;
    o[0] = (bf16_t)v[0]; o[1] = (bf16_t)v[1];
    o[2] = (bf16_t)v[2]; o[3] = (bf16_t)v[3];
    *(bf16x4*)(out + i) = o;
}

// ---------------------------------------------------------------------------
// CSR build: histogram -> hierarchical exclusive scan -> placement
// ---------------------------------------------------------------------------
__global__ __launch_bounds__(256) void hist_k(const int* __restrict__ idx,
                                              int* __restrict__ counts, int nE) {
    int e = blockIdx.x * 256 + threadIdx.x;
    if (e < nE) atomicAdd(&counts[idx[e]], 1);
}

__global__ __launch_bounds__(256) void scan1_k(const int* __restrict__ in,
                                               int* __restrict__ out,
                                               int* __restrict__ bsum, int n) {
    __shared__ int tmp[256];
    const int t = threadIdx.x;
    const long base = (long)blockIdx.x * 1024 + (long)t * 4;
    int v[4];
    int s = 0;
#pragma unroll
    for (int j = 0; j < 4; j++) {
        long i = base + j;
        int x = (i < n) ? in[i] : 0;
        v[j] = s;
        s += x;
    }
    tmp[t] = s;
    __syncthreads();
    int inc = s;
    for (int off = 1; off < 256; off <<= 1) {
        int y = (t >= off) ? tmp[t - off] : 0;
        __syncthreads();
        inc += y;
        tmp[t] = inc;
        __syncthreads();
    }
    const int toff = inc - s;
#pragma unroll
    for (int j = 0; j < 4; j++) {
        long i = base + j;
        if (i < n) out[i] = v[j] + toff;
    }
    if (t == 255) bsum[blockIdx.x] = inc;
}

__global__ __launch_bounds__(256) void scan2_k(int* __restrict__ bsum, int nb) {
    __shared__ int tmp[256];
    const int t = threadIdx.x;
    int x = (t < nb) ? bsum[t] : 0;
    tmp[t] = x;
    __syncthreads();
    int inc = x;
    for (int off = 1; off < 256; off <<= 1) {
        int y = (t >= off) ? tmp[t - off] : 0;
        __syncthreads();
        inc += y;
        tmp[t] = inc;
        __syncthreads();
    }
    if (t < nb) bsum[t] = inc - x;
}

__global__ __launch_bounds__(256) void scan3_k(const int* __restrict__ partial,
                                               const int* __restrict__ bsum,
                                               int* __restrict__ rowptr,
                                               int* __restrict__ work,
                                               int n, int total) {
    long i = (long)blockIdx.x * 256 + threadIdx.x;
    if (i < n) {
        int v = partial[i] + bsum[i >> 10];
        rowptr[i] = v;
        work[i] = v;
    }
    if (i == 0) rowptr[n] = total;
}

__global__ __launch_bounds__(256) void csr_place(const int* __restrict__ idx,
                                                 const int* __restrict__ gsrc,
                                                 int* __restrict__ work,
                                                 int* __restrict__ gat, int nE) {
    int e = blockIdx.x * 256 + threadIdx.x;
    if (e < nE) {
        int p = atomicAdd(&work[idx[e]], 1);
        gat[p] = gsrc[e];
    }
}

// ---------------------------------------------------------------------------
// Gather-based segment sums over bf16 features (one wave per segment).
// ---------------------------------------------------------------------------
__global__ __launch_bounds__(256) void segsum_ginb(const bf16_t* __restrict__ X,
                                                   const float* __restrict__ epsPtr,
                                                   const int* __restrict__ rowptr,
                                                   const int* __restrict__ gat,
                                                   bf16_t* __restrict__ out, int nseg) {
    int seg = blockIdx.x * 4 + (threadIdx.x >> 6);
    if (seg >= nseg) return;
    int lane = threadIdx.x & 63;
    float alpha = 1.f + epsPtr[0];
    bf16x2 xv = *((const bf16x2*)(X + (size_t)seg * HDIM) + lane);
    float a0 = alpha * (float)xv[0], a1 = alpha * (float)xv[1];
    int s0 = rowptr[seg], s1 = rowptr[seg + 1];
    for (int e = s0; e < s1; e++) {
        int g = gat[e];
        bf16x2 v = *((const bf16x2*)(X + (size_t)g * HDIM) + lane);
        a0 += (float)v[0];
        a1 += (float)v[1];
    }
    bf16x2 o;
    o[0] = (bf16_t)a0;
    o[1] = (bf16_t)a1;
    *((bf16x2*)(out + (size_t)seg * HDIM) + lane) = o;
}

__global__ __launch_bounds__(256) void segsum_b16(const bf16_t* __restrict__ X,
                                                  const int* __restrict__ rowptr,
                                                  const int* __restrict__ gat,
                                                  bf16_t* __restrict__ out, int nseg) {
    int seg = blockIdx.x * 4 + (threadIdx.x >> 6);
    if (seg >= nseg) return;
    int lane = threadIdx.x & 63;
    float a0 = 0.f, a1 = 0.f;
    int s0 = rowptr[seg], s1 = rowptr[seg + 1];
    for (int e = s0; e < s1; e++) {
        int g = gat[e];
        bf16x2 v = *((const bf16x2*)(X + (size_t)g * HDIM) + lane);
        a0 += (float)v[0];
        a1 += (float)v[1];
    }
    bf16x2 o;
    o[0] = (bf16_t)a0;
    o[1] = (bf16_t)a1;
    *((bf16x2*)(out + (size_t)seg * HDIM) + lane) = o;
}

// ---------------------------------------------------------------------------
// BN finalize
// ---------------------------------------------------------------------------
__global__ void bn_finalize(const float* __restrict__ cs, const float* __restrict__ cs2,
                            const float* __restrict__ g, const float* __restrict__ b,
                            float* __restrict__ scale, float* __restrict__ shift,
                            int C, float invN) {
    int c = blockIdx.x * blockDim.x + threadIdx.x;
    if (c >= C) return;
    float m = cs[c] * invN;
    float v = cs2[c] * invN - m * m;
    float sc = g[c] * rsqrtf(v + 1e-5f);
    scale[c] = sc;
    shift[c] = b[c] - m * sc;
}

// ---------------------------------------------------------------------------
// LDS-staged fused GEMM (m97-style): block tile 128x128, BK=64, 4 waves.
// A bf16 [M x K] row-major; Wt bf16 [Nc x K] n-major.
// Staging: global_load_lds 16B/lane, XOR-swizzled chunks (chunk j of row r
// holds global chunk j^(r&7)) -> ds_read_b128 frag reads are 2-way = free.
// bnfold: A := relu(A*bnScale[k]+bnShift[k]) before MFMA.
// flags: 1 relu, 2 accumulate into outF, 4 column stats.
// outB2: optional bf16 shadow copy of the fp32 output.
// ---------------------------------------------------------------------------
__global__ __launch_bounds__(256) void gemm_tiled(
    const bf16_t* __restrict__ Ab,
    const float* __restrict__ bnScale, const float* __restrict__ bnShift,
    const bf16_t* __restrict__ Wt, const float* __restrict__ bias,
    int M, int K, int Nc,
    float* __restrict__ outF, bf16_t* __restrict__ outB,
    bf16_t* __restrict__ outB2,
    float* __restrict__ colsum, float* __restrict__ colsumsq,
    int bnfold, int flags) {
    __shared__ bf16_t lA[128 * 64];
    __shared__ bf16_t lB[128 * 64];
    const int tid = threadIdx.x;
    const int w = tid >> 6, lane = tid & 63;
    const int q = lane >> 4, lm = lane & 15;
    const int wm = w & 1, wn = w >> 1;
    const int rowBase0 = blockIdx.x * 128;
    const int colBase0 = blockIdx.y * 128;
    const int sr = lane >> 3, sj = lane & 7;
    const int sg = sj ^ sr;  // source chunk for XOR-swizzled store

    f32x4 acc[4][4];
#pragma unroll
    for (int a = 0; a < 4; a++)
#pragma unroll
        for (int b = 0; b < 4; b++) acc[a][b] = f32x4{0.f, 0.f, 0.f, 0.f};

    const int kTiles = K >> 6;
    for (int kt = 0; kt < kTiles; kt++) {
        const int k0 = kt << 6;
        if (kt) __syncthreads();
#pragma unroll
        for (int is = 0; is < 4; is++) {
            const int rl = w * 32 + is * 8;  // wave-uniform group base
            int gr = rowBase0 + rl + sr;
            if (gr > M - 1) gr = M - 1;
            GLOAD_LDS16(Ab + (size_t)gr * K + k0 + sg * 8, lA + rl * 64);
            const int cl = colBase0 + rl + sr;
            GLOAD_LDS16(Wt + (size_t)cl * K + k0 + sg * 8, lB + rl * 64);
        }
        __builtin_amdgcn_s_waitcnt(0);
        __syncthreads();
#pragma unroll
        for (int ks = 0; ks < 2; ks++) {
            const int sc = ((ks << 2) + q) ^ (lm & 7);
            bf16x8 af[4], bfr[4];
#pragma unroll
            for (int mi = 0; mi < 4; mi++)
                af[mi] = *(const bf16x8*)(lA + (wm * 64 + mi * 16 + lm) * 64 + sc * 8);
#pragma unroll
            for (int ni = 0; ni < 4; ni++)
                bfr[ni] = *(const bf16x8*)(lB + (wn * 64 + ni * 16 + lm) * 64 + sc * 8);
            if (bnfold) {
                const int kk = k0 + ks * 32 + q * 8;
                f32x4 s0 = ((const f32x4*)(bnScale + kk))[0];
                f32x4 s1v = ((const f32x4*)(bnScale + kk))[1];
                f32x4 h0 = ((const f32x4*)(bnShift + kk))[0];
                f32x4 h1 = ((const f32x4*)(bnShift + kk))[1];
                float sc8[8] = {s0[0], s0[1], s0[2], s0[3], s1v[0], s1v[1], s1v[2], s1v[3]};
                float sh8[8] = {h0[0], h0[1], h0[2], h0[3], h1[0], h1[1], h1[2], h1[3]};
#pragma unroll
                for (int mi = 0; mi < 4; mi++)
#pragma unroll
                    for (int j = 0; j < 8; j++) {
                        float f = fmaxf((float)af[mi][j] * sc8[j] + sh8[j], 0.f);
                        af[mi][j] = (bf16_t)f;
                    }
            }
#pragma unroll
            for (int mi = 0; mi < 4; mi++)
#pragma unroll
                for (int ni = 0; ni < 4; ni++)
                    acc[mi][ni] = __builtin_amdgcn_mfma_f32_16x16x32_bf16(
                        af[mi], bfr[ni], acc[mi][ni], 0, 0, 0);
        }
    }

    const bool doRelu = (flags & 1), doAccum = (flags & 2), doStats = (flags & 4);
#pragma unroll
    for (int ni = 0; ni < 4; ni++) {
        const int col = colBase0 + wn * 64 + ni * 16 + lm;
        const float bv = bias[col];
        float s1 = 0.f, s2 = 0.f;
#pragma unroll
        for (int mi = 0; mi < 4; mi++) {
#pragma unroll
            for (int r = 0; r < 4; r++) {
                const int row = rowBase0 + wm * 64 + mi * 16 + q * 4 + r;
                if (row < M) {
                    float v = acc[mi][ni][r] + bv;
                    if (doStats) { s1 += v; s2 += v * v; }
                    if (doRelu) v = fmaxf(v, 0.f);
                    const size_t o = (size_t)row * Nc + col;
                    if (outF) {
                        float nv = doAccum ? outF[o] + v : v;
                        outF[o] = nv;
                        if (outB2) outB2[o] = (bf16_t)nv;
                    } else {
                        outB[o] = (bf16_t)v;
                    }
                }
            }
        }
        if (doStats) {
            s1 += __shfl_xor(s1, 16);
            s1 += __shfl_xor(s1, 32);
            s2 += __shfl_xor(s2, 16);
            s2 += __shfl_xor(s2, 32);
            if (q == 0) {
                atomicAdd(&colsum[col], s1);
                atomicAdd(&colsumsq[col], s2);
            }
        }
    }
}

// ---------------------------------------------------------------------------
extern "C" void kernel_launch(void* const* d_in, const int* in_sizes, int n_in,
                              void* d_out, int out_size, void* d_ws, size_t ws_size,
                              hipStream_t stream) {
    const float* x_in   = (const float*)d_in[0];
    const int*   ei     = (const int*)d_in[1];
    const int*   se0    = (const int*)d_in[2];
    const int*   se1    = (const int*)d_in[3];
    const float* msg_w1 = (const float*)d_in[4];
    const float* msg_b1 = (const float*)d_in[5];
    const float* bn_g   = (const float*)d_in[6];
    const float* bn_b   = (const float*)d_in[7];
    const float* msg_w2 = (const float*)d_in[8];
    const float* msg_b2 = (const float*)d_in[9];
    const float* eps_g  = (const float*)d_in[10];
    const float* n2s_w1 = (const float*)d_in[11];
    const float* n2s_b1 = (const float*)d_in[12];
    const float* n2s_w2 = (const float*)d_in[13];
    const float* n2s_b2 = (const float*)d_in[14];
    const float* s2n_w1 = (const float*)d_in[15];
    const float* s2n_b1 = (const float*)d_in[16];
    const float* s2n_w2 = (const float*)d_in[17];
    const float* s2n_b2 = (const float*)d_in[18];
    const float* out_w1 = (const float*)d_in[19];
    const float* out_b1 = (const float*)d_in[20];
    const float* out_w2 = (const float*)d_in[21];
    const float* out_b2 = (const float*)d_in[22];
    float* out = (float*)d_out;

    char* ws = (char*)d_ws;
    size_t off = 0;
    auto alloc = [&](size_t bytes) -> char* {
        char* p = ws + off;
        off += (bytes + 255) & ~(size_t)255;
        return p;
    };
    float*  xbuf  = (float*)alloc((size_t)N_NODES * HDIM * 4);   // fp32 residual x
    bf16_t* xbf   = (bf16_t*)alloc((size_t)N_NODES * HDIM * 2);  // bf16 shadow of x
    bf16_t* xcomb = (bf16_t*)alloc((size_t)N_NODES * HDIM * 2);  // gin-comb / s2n msg
    bf16_t* hbuf  = (bf16_t*)alloc((size_t)N_NODES * H2DIM * 2);
    bf16_t* sxsum = (bf16_t*)alloc((size_t)NSUB_G * HDIM * 2);
    bf16_t* shbuf = (bf16_t*)alloc((size_t)NSUB_G * H2DIM * 2);
    bf16_t* sxout = (bf16_t*)alloc((size_t)NSUB_G * HDIM * 2);
    const size_t WSZ = (size_t)HDIM * H2DIM;
    bf16_t* wt_msg1 = (bf16_t*)alloc(NLAYER * WSZ * 2);
    bf16_t* wt_msg2 = (bf16_t*)alloc(NLAYER * WSZ * 2);
    bf16_t* wt_n2s1 = (bf16_t*)alloc(NLAYER * NSUBT * WSZ * 2);
    bf16_t* wt_n2s2 = (bf16_t*)alloc(NLAYER * NSUBT * WSZ * 2);
    bf16_t* wt_s2n1 = (bf16_t*)alloc(NLAYER * NSUBT * WSZ * 2);
    bf16_t* wt_s2n2 = (bf16_t*)alloc(NLAYER * NSUBT * WSZ * 2);
    bf16_t* wt_out1 = (bf16_t*)alloc(WSZ * 2);
    bf16_t* wt_out2 = (bf16_t*)alloc(WSZ * 2);
    float* colsum   = (float*)alloc(H2DIM * 4);
    float* colsumsq = (float*)alloc(H2DIM * 4);
    float* bnscale  = (float*)alloc(H2DIM * 4);
    float* bnshift  = (float*)alloc(H2DIM * 4);
    int* rp_gin   = (int*)alloc((N_NODES + 1) * 4);
    int* gat_gin  = (int*)alloc((size_t)E_EDGES * 4);
    int* rp_n2s0  = (int*)alloc((NSUB_G + 1) * 4);
    int* gat_n2s0 = (int*)alloc((size_t)ESUB_E * 4);
    int* rp_n2s1  = (int*)alloc((NSUB_G + 1) * 4);
    int* gat_n2s1 = (int*)alloc((size_t)ESUB_E * 4);
    int* rp_s2n0  = (int*)alloc((N_NODES + 1) * 4);
    int* gat_s2n0 = (int*)alloc((size_t)ESUB_E * 4);
    int* rp_s2n1  = (int*)alloc((N_NODES + 1) * 4);
    int* gat_s2n1 = (int*)alloc((size_t)ESUB_E * 4);
    int* counts  = (int*)alloc((N_NODES + 1) * 4);
    int* partial = (int*)alloc((size_t)N_NODES * 4);
    int* bsum    = (int*)alloc(512 * 4);
    (void)ws_size; (void)in_sizes; (void)n_in; (void)out_size;

    auto tr = [&](const float* W, bf16_t* Wt, int K, int Nc, int batch) {
        long total = (long)batch * K * Nc;
        int blocks = (int)((total + 255) / 256);
        transpose_w<<<blocks, 256, 0, stream>>>(W, Wt, K, Nc, total);
    };
    tr(msg_w1, wt_msg1, HDIM, H2DIM, NLAYER);
    tr(msg_w2, wt_msg2, H2DIM, HDIM, NLAYER);
    tr(n2s_w1, wt_n2s1, HDIM, H2DIM, NLAYER * NSUBT);
    tr(n2s_w2, wt_n2s2, H2DIM, HDIM, NLAYER * NSUBT);
    tr(s2n_w1, wt_s2n1, HDIM, H2DIM, NLAYER * NSUBT);
    tr(s2n_w2, wt_s2n2, H2DIM, HDIM, NLAYER * NSUBT);
    tr(out_w1, wt_out1, HDIM, H2DIM, 1);
    tr(out_w2, wt_out2, H2DIM, OUTD, 1);

    auto build_csr = [&](const int* idx, const int* gsrc, int nE, int nseg,
                         int* rowptr, int* gat) {
        hipMemsetAsync(counts, 0, (size_t)nseg * 4, stream);
        hist_k<<<(nE + 255) / 256, 256, 0, stream>>>(idx, counts, nE);
        int nb = (nseg + 1023) / 1024;
        scan1_k<<<nb, 256, 0, stream>>>(counts, partial, bsum, nseg);
        scan2_k<<<1, 256, 0, stream>>>(bsum, nb);
        scan3_k<<<(nseg + 255) / 256, 256, 0, stream>>>(partial, bsum, rowptr,
                                                        counts, nseg, nE);
        csr_place<<<(nE + 255) / 256, 256, 0, stream>>>(idx, gsrc, counts, gat, nE);
    };
    const int* src = ei;
    const int* dst = ei + E_EDGES;
    build_csr(dst, src, E_EDGES, N_NODES, rp_gin, gat_gin);
    build_csr(se0 + ESUB_E, se0, ESUB_E, NSUB_G, rp_n2s0, gat_n2s0);
    build_csr(se1 + ESUB_E, se1, ESUB_E, NSUB_G, rp_n2s1, gat_n2s1);
    build_csr(se0, se0 + ESUB_E, ESUB_E, N_NODES, rp_s2n0, gat_s2n0);
    build_csr(se1, se1 + ESUB_E, ESUB_E, N_NODES, rp_s2n1, gat_s2n1);

    hipMemcpyAsync(xbuf, x_in, (size_t)N_NODES * HDIM * 4,
                   hipMemcpyDeviceToDevice, stream);
    {
        long n = (long)N_NODES * HDIM;
        cast_f2b<<<(int)((n / 4 + 255) / 256), 256, 0, stream>>>(x_in, xbf, n);
    }

    auto gemm = [&](const bf16_t* Ab, const float* bnS, const float* bnH,
                    const bf16_t* Wt, const float* bias, int M, int K, int Nc,
                    float* oF, bf16_t* oB, bf16_t* oB2,
                    float* cs, float* cs2, int bnfold, int flags) {
        dim3 g((M + 127) / 128, Nc / 128);
        gemm_tiled<<<g, 256, 0, stream>>>(Ab, bnS, bnH, Wt, bias, M, K, Nc,
                                          oF, oB, oB2, cs, cs2, bnfold, flags);
    };

    for (int i = 0; i < NLAYER; i++) {
        // GIN aggregation fused with (1+eps)x combine -> bf16
        segsum_ginb<<<(N_NODES + 3) / 4, 256, 0, stream>>>(
            xbf, eps_g + i, rp_gin, gat_gin, xcomb, N_NODES);
        // h = xcomb @ W1 + b1 ; column stats for BN
        hipMemsetAsync(colsum, 0, H2DIM * 4, stream);
        hipMemsetAsync(colsumsq, 0, H2DIM * 4, stream);
        gemm(xcomb, nullptr, nullptr,
             wt_msg1 + (size_t)i * WSZ, msg_b1 + (size_t)i * H2DIM,
             N_NODES, HDIM, H2DIM, nullptr, hbuf, nullptr, colsum, colsumsq, 0, 4);
        bn_finalize<<<1, 256, 0, stream>>>(colsum, colsumsq, bn_g + (size_t)i * H2DIM,
                                           bn_b + (size_t)i * H2DIM, bnscale, bnshift,
                                           H2DIM, 1.0f / N_NODES);
        // x = relu(BN(h)) @ W2 + b2   (fp32 + bf16 shadow)
        gemm(hbuf, bnscale, bnshift,
             wt_msg2 + (size_t)i * WSZ, msg_b2 + (size_t)i * HDIM,
             N_NODES, H2DIM, HDIM, xbuf, nullptr, xbf, nullptr, nullptr, 1, 0);

        for (int s = 0; s < NSUBT; s++) {
            const int* rp_n2s = (s == 0 ? rp_n2s0 : rp_n2s1);
            const int* gt_n2s = (s == 0 ? gat_n2s0 : gat_n2s1);
            const int* rp_s2n = (s == 0 ? rp_s2n0 : rp_s2n1);
            const int* gt_s2n = (s == 0 ? gat_s2n0 : gat_s2n1);
            const size_t widx = ((size_t)i * NSUBT + s) * WSZ;
            const size_t b1o = ((size_t)i * NSUBT + s) * H2DIM;
            const size_t b2o = ((size_t)i * NSUBT + s) * HDIM;
            // sx = segment_sum(x[row], col)
            segsum_b16<<<(NSUB_G + 3) / 4, 256, 0, stream>>>(
                xbf, rp_n2s, gt_n2s, sxsum, NSUB_G);
            // sx = relu(sx@w1+b1)@w2+b2
            gemm(sxsum, nullptr, nullptr, wt_n2s1 + widx, n2s_b1 + b1o,
                 NSUB_G, HDIM, H2DIM, nullptr, shbuf, nullptr, nullptr, nullptr, 0, 1);
            gemm(shbuf, nullptr, nullptr, wt_n2s2 + widx, n2s_b2 + b2o,
                 NSUB_G, H2DIM, HDIM, nullptr, sxout, nullptr, nullptr, nullptr, 0, 0);
            // msg = segment_sum(sx[col], row)
            segsum_b16<<<(N_NODES + 3) / 4, 256, 0, stream>>>(
                sxout, rp_s2n, gt_s2n, xcomb, N_NODES);
            // x += relu(msg@w1+b1)@w2+b2   (fp32 + bf16 shadow)
            gemm(xcomb, nullptr, nullptr, wt_s2n1 + widx, s2n_b1 + b1o,
                 N_NODES, HDIM, H2DIM, nullptr, hbuf, nullptr, nullptr, nullptr, 0, 1);
            gemm(hbuf, nullptr, nullptr, wt_s2n2 + widx, s2n_b2 + b2o,
                 N_NODES, H2DIM, HDIM, xbuf, nullptr, xbf, nullptr, nullptr, 0, 2);
        }
    }
    // output head
    gemm(xbf, nullptr, nullptr, wt_out1, out_b1,
         N_NODES, HDIM, H2DIM, nullptr, hbuf, nullptr, nullptr, nullptr, 0, 1);
    gemm(hbuf, nullptr, nullptr, wt_out2, out_b2,
         N_NODES, H2DIM, OUTD, out, nullptr, nullptr, nullptr, nullptr, 0, 0);
}